// Round 9
// baseline (216.465 us; speedup 1.0000x reference)
//
#include <hip/hip_runtime.h>
#include <hip/hip_fp16.h>

#define M_TOTAL 512
#define N_TOTAL 11008
#define K_TOTAL 4096
#define BM 128
#define BN 64
#define BK 64
#define NT (K_TOTAL / BK)  // 64
#define NUM_GROUPS (N_TOTAL * K_TOTAL / 32)  // 1409024
#define LDK 72             // fallback kernel's padded stride

typedef short bf16x8 __attribute__((ext_vector_type(8)));
typedef _Float16 f16x8 __attribute__((ext_vector_type(8)));
typedef float f32x4 __attribute__((ext_vector_type(4)));
typedef float f32x16 __attribute__((ext_vector_type(16)));

// pack two fp32 into two bf16 (round-half-up) -> uint32 (fallback path)
__device__ __forceinline__ unsigned int pack2_bf16(float f0, float f1) {
    unsigned int u0 = __builtin_bit_cast(unsigned int, f0) + 0x8000u;
    unsigned int u1 = __builtin_bit_cast(unsigned int, f1) + 0x8000u;
    return (u0 >> 16) | (u1 & 0xFFFF0000u);
}

// Per-wave dtype detection for weight_norm: 0=f32, 1=f16, 2=bf16.
__device__ __forceinline__ int detect_mode_wave(const void* __restrict__ wn) {
    const int lane = threadIdx.x & 63;
    const unsigned short* u16 = (const unsigned short*)wn;
    const float* f32p = (const float*)wn;
    const float vb = __builtin_bit_cast(float, (unsigned int)u16[lane] << 16);
    const float vh = __half2float(__builtin_bit_cast(__half, u16[lane]));
    const float vf = f32p[lane];
    const unsigned long long mb = __ballot(vb > 0.005f && vb < 0.12f);
    const unsigned long long mh = __ballot(vh > 0.005f && vh < 0.12f);
    (void)vf;
    return (mb == ~0ull) ? 2 : ((mh == ~0ull) ? 1 : 0);
}

// x fp32 [512][4096] -> xh_t f16 tiled [kc=k/8][m][k&7]  (A-fragment order:
// lane m=l&31 reads 16 B at kc*8192 + m*16 -> 512 B dense across lanes)
__global__ void __launch_bounds__(256)
convert_x_t_kernel(const float* __restrict__ x, unsigned short* __restrict__ xt) {
    __shared__ unsigned short tile[32][72];  // 32 m x 64 k, padded stride
    const int t  = threadIdx.x;
    const int mb = (blockIdx.x & 15) * 32;   // 16 m-blocks
    const int kb = (blockIdx.x >> 4) * 64;   // 64 k-blocks
    {
        const int m  = t >> 3;       // 0..31
        const int kq = t & 7;        // 8 f32 each
        const float* src = &x[(size_t)(mb + m) * K_TOTAL + kb + kq * 8];
        const float4 v0 = *(const float4*)src;
        const float4 v1 = *(const float4*)(src + 4);
        unsigned int p0 = __builtin_bit_cast(unsigned int, __builtin_amdgcn_cvt_pkrtz(v0.x, v0.y));
        unsigned int p1 = __builtin_bit_cast(unsigned int, __builtin_amdgcn_cvt_pkrtz(v0.z, v0.w));
        unsigned int p2 = __builtin_bit_cast(unsigned int, __builtin_amdgcn_cvt_pkrtz(v1.x, v1.y));
        unsigned int p3 = __builtin_bit_cast(unsigned int, __builtin_amdgcn_cvt_pkrtz(v1.z, v1.w));
        *(uint4*)&tile[m][kq * 8] = make_uint4(p0, p1, p2, p3);
    }
    __syncthreads();
    {
        const int kc = t >> 5;       // 0..7
        const int mm = t & 31;       // 0..31
        const uint4 v = *(const uint4*)&tile[mm][kc * 8];
        // dest: (kb/8 + kc) slab, row mb+mm -> 16 B; lanes mm contiguous
        *(uint4*)&xt[(size_t)((kb >> 3) + kc) * (M_TOTAL * 8) + (size_t)(mb + mm) * 8] = v;
    }
}

// one-shot norm prep: per group pack (s=2n/7 lo16, c=-n hi16) as one u32
__global__ void __launch_bounds__(512)
norm_pack_kernel(const void* __restrict__ wn, unsigned int* __restrict__ np) {
    const int mode = detect_mode_wave(wn);
    const int g = blockIdx.x * 512 + threadIdx.x;
    if (g >= NUM_GROUPS) return;
    float n;
    if (mode == 0)      n = ((const float*)wn)[g];
    else if (mode == 1) n = __half2float(((const __half*)wn)[g]);
    else                n = __builtin_bit_cast(float,
                            (unsigned int)((const unsigned short*)wn)[g] << 16);
    np[g] = __builtin_bit_cast(unsigned int,
                __builtin_amdgcn_cvt_pkrtz(n * (2.0f / 7.0f), -n));
}

// ---- main kernel: 512 thr, 8 waves 4m x 2n of 32x32 tiles; A global->reg,
// ---- B decode->LDS (8 KB x2 only); mfma_f32_32x32x16_f16
__global__ void __launch_bounds__(512, 5)
l3b_gemm_pipe(const _Float16* __restrict__ xh, const int* __restrict__ wq,
              const unsigned int* __restrict__ np, const float* __restrict__ bias,
              float* __restrict__ out)
{
    __shared__ _Float16 Bs0[BN * 64];  // 8 KB
    __shared__ _Float16 Bs1[BN * 64];  // 8 KB

    const int tid  = threadIdx.x;

    // XCD swizzle (R5+: FETCH 148->56 MB)
    const int bid = blockIdx.x;                 // 0..687
    const int w   = (bid & 7) * 86 + (bid >> 3);
    const int m0  = (w & 3) * BM;
    const int n0  = (w >> 2) * BN;

    const int wid  = tid >> 6;   // 0..7
    const int lane = tid & 63;
    const int lr   = lane & 31;  // fragment row (m or n)
    const int lh   = lane >> 5;  // k-half
    const int wm   = (wid >> 1) * 32;   // 0,32,64,96
    const int wn_  = (wid & 1) * 32;    // 0,32

    // B decode mapping (verbatim R8, verified): 1 thread per 8 weights
    const int gl   = tid >> 2;     // 0..127 (64 n x 2 k-groups)
    const int sub  = tid & 3;
    const int bn_l = gl >> 1;      // 0..63
    const int kg   = gl & 1;
    const int ldsB = (bn_l << 6) + (((kg * 4 + sub) ^ (bn_l & 7)) << 3);

    // A global base: lane l reads 16 B at slab kc = it*8 + s*2 + lh, row m0+wm+lr
    const _Float16* aBase = xh + (size_t)(m0 + wm + lr) * 8;

    auto loadA = [&](int it, f16x8& a0, f16x8& a1, f16x8& a2, f16x8& a3) {
        const _Float16* p = aBase + (size_t)(it * 8 + lh) * (M_TOTAL * 8);
        a0 = *(const f16x8*)(p);
        a1 = *(const f16x8*)(p + 2 * (M_TOTAL * 8));
        a2 = *(const f16x8*)(p + 4 * (M_TOTAL * 8));
        a3 = *(const f16x8*)(p + 6 * (M_TOTAL * 8));
    };

    auto loadB = [&](int it, int& b0, int& b1, int& b2, unsigned int& npk) {
        const int g    = (n0 + bn_l) * (K_TOTAL / 32) + it * 2 + kg;
        const int base = g * 12 + sub * 3;
        b0 = wq[base]; b1 = wq[base + 1]; b2 = wq[base + 2];
        npk = np[g];
    };

    const __half2 h1024 = __builtin_bit_cast(__half2, 0x64006400u);
    auto decodeB = [&](int b0, int b1, int b2, unsigned int npk, _Float16* Bb) {
        const __half2 ss = __builtin_bit_cast(__half2,
            __builtin_amdgcn_perm(npk, npk, 0x01000100u));
        const __half2 cc = __builtin_bit_cast(__half2,
            __builtin_amdgcn_perm(npk, npk, 0x03020302u));
        const unsigned int bits =
            (unsigned)b0 | ((unsigned)b1 << 8) | ((unsigned)b2 << 16);
        unsigned int packs[4];
#pragma unroll
        for (int j = 0; j < 4; ++j) {
            const unsigned int q0 = (bits >> (6 * j)) & 7;
            const unsigned int q1 = (bits >> (6 * j + 3)) & 7;
            const __half2 h = __builtin_bit_cast(__half2,
                (q0 | (q1 << 16)) | 0x64006400u);
            const __half2 q = __hsub2(h, h1024);
            packs[j] = __builtin_bit_cast(unsigned int, __hfma2(q, ss, cc));
        }
        *(uint4*)&Bb[ldsB] = make_uint4(packs[0], packs[1], packs[2], packs[3]);
    };

    f32x16 acc = {};

    // B-frag read geometry: row = wn_+lr, logical chunk = s*2+lh, phys ^= row&7
    const int bRow  = wn_ + lr;
    const int bOff  = bRow << 6;
    const int bSwz  = bRow & 7;

    auto mfmaTile = [&](const _Float16* Bb, const f16x8& a0, const f16x8& a1,
                        const f16x8& a2, const f16x8& a3) {
        f16x8 bF0 = *(const f16x8*)&Bb[bOff + (((0 + lh) ^ bSwz) << 3)];
        f16x8 bF1 = *(const f16x8*)&Bb[bOff + (((2 + lh) ^ bSwz) << 3)];
        f16x8 bF2 = *(const f16x8*)&Bb[bOff + (((4 + lh) ^ bSwz) << 3)];
        f16x8 bF3 = *(const f16x8*)&Bb[bOff + (((6 + lh) ^ bSwz) << 3)];
        acc = __builtin_amdgcn_mfma_f32_32x32x16_f16(a0, bF0, acc, 0, 0, 0);
        acc = __builtin_amdgcn_mfma_f32_32x32x16_f16(a1, bF1, acc, 0, 0, 0);
        acc = __builtin_amdgcn_mfma_f32_32x32x16_f16(a2, bF2, acc, 0, 0, 0);
        acc = __builtin_amdgcn_mfma_f32_32x32x16_f16(a3, bF3, acc, 0, 0, 0);
    };

    // named register sets (no dynamic indexing)
    f16x8 aC0, aC1, aC2, aC3, aN0, aN1, aN2, aN3;
    int w00, w01, w02; unsigned int n0p;   // wq set0
    int w10, w11, w12; unsigned int n1p;   // set1
    int w20, w21, w22; unsigned int n2p;   // set2
    int w30, w31, w32; unsigned int n3p;   // set3

    // prologue
    loadB(0, w00, w01, w02, n0p);
    loadB(1, w10, w11, w12, n1p);
    loadB(2, w20, w21, w22, n2p);
    loadA(0, aC0, aC1, aC2, aC3);
    decodeB(w00, w01, w02, n0p, Bs0);
    __syncthreads();

    // x4 unrolled: at sub-iter t: loadA(t+1), loadB(t+3), decodeB(t+1), mfma(t)
    for (int it = 0; it < NT; it += 4) {
        {   // t = it (cur Bs0 / aC)
            const int t = it;
            if (t + 1 < NT) loadA(t + 1, aN0, aN1, aN2, aN3);
            if (t + 3 < NT) loadB(t + 3, w30, w31, w32, n3p);
            if (t + 1 < NT) decodeB(w10, w11, w12, n1p, Bs1);
            mfmaTile(Bs0, aC0, aC1, aC2, aC3);
            __syncthreads();
        }
        {   // t = it+1 (cur Bs1 / aN)
            const int t = it + 1;
            if (t + 1 < NT) loadA(t + 1, aC0, aC1, aC2, aC3);
            if (t + 3 < NT) loadB(t + 3, w00, w01, w02, n0p);
            if (t + 1 < NT) decodeB(w20, w21, w22, n2p, Bs0);
            mfmaTile(Bs1, aN0, aN1, aN2, aN3);
            __syncthreads();
        }
        {   // t = it+2 (cur Bs0 / aC)
            const int t = it + 2;
            if (t + 1 < NT) loadA(t + 1, aN0, aN1, aN2, aN3);
            if (t + 3 < NT) loadB(t + 3, w10, w11, w12, n1p);
            if (t + 1 < NT) decodeB(w30, w31, w32, n3p, Bs1);
            mfmaTile(Bs0, aC0, aC1, aC2, aC3);
            __syncthreads();
        }
        {   // t = it+3 (cur Bs1 / aN)
            const int t = it + 3;
            if (t + 1 < NT) loadA(t + 1, aC0, aC1, aC2, aC3);
            if (t + 3 < NT) loadB(t + 3, w20, w21, w22, n2p);
            if (t + 1 < NT) decodeB(w00, w01, w02, n0p, Bs0);
            mfmaTile(Bs1, aN0, aN1, aN2, aN3);
            __syncthreads();
        }
    }

    // epilogue: 32x32 C/D layout: col = lane&31, row = (r&3) + 8*(r>>2) + 4*lh
    const int o  = n0 + wn_ + lr;
    const float bv = bias[o];
#pragma unroll
    for (int r = 0; r < 16; ++r) {
        const int m = m0 + wm + (r & 3) + ((r >> 2) << 3) + (lh << 2);
        out[(size_t)m * N_TOTAL + o] = acc[r] + bv;
    }
}

// ---------------- fallback (r2-style bf16) if ws too small ----------------
__global__ void __launch_bounds__(256)
l3b_gemm_kernel(const float* __restrict__ x, const int* __restrict__ wq,
                const void* __restrict__ wnorm, const float* __restrict__ bias,
                float* __restrict__ out)
{
    __shared__ unsigned short As[128 * LDK];
    __shared__ unsigned short Bs[64 * LDK];

    const int mode = detect_mode_wave(wnorm);
    const int tid  = threadIdx.x;
    const int m0   = blockIdx.y * 128;
    const int n0   = blockIdx.x * 64;
    const int wid  = tid >> 6;
    const int lane = tid & 63;
    const int quad = lane >> 4;
    const int lm   = lane & 15;
    const int wm   = (wid >> 1) * 64;
    const int wn   = (wid & 1) * 32;

    f32x4 acc[4][2];
#pragma unroll
    for (int i = 0; i < 4; ++i)
#pragma unroll
        for (int j = 0; j < 2; ++j) acc[i][j] = (f32x4){0.f, 0.f, 0.f, 0.f};

    const int ar = tid >> 4;
    const int ac = (tid & 15) * 4;
    const int gin      = tid >> 1;
    const int half     = tid & 1;
    const int bn_local = gin >> 1;
    const int bkg      = gin & 1;

    for (int it = 0; it < NT; ++it) {
        const int k0 = it * BK;
        __syncthreads();
#pragma unroll
        for (int p = 0; p < 8; ++p) {
            const int row = p * 16 + ar;
            const float4 v = *(const float4*)&x[(m0 + row) * K_TOTAL + k0 + ac];
            *(uint2*)&As[row * LDK + ac] =
                make_uint2(pack2_bf16(v.x, v.y), pack2_bf16(v.z, v.w));
        }
        {
            const int g    = (n0 + bn_local) * (K_TOTAL / 32) + it * 2 + bkg;
            const int base = g * 12 + half * 6;
            const int2 w0 = *(const int2*)&wq[base];
            const int2 w1 = *(const int2*)&wq[base + 2];
            const int2 w2 = *(const int2*)&wq[base + 4];
            float nrm;
            if (mode == 0)      nrm = ((const float*)wnorm)[g];
            else if (mode == 1) nrm = __half2float(((const __half*)wnorm)[g]);
            else                nrm = __builtin_bit_cast(float,
                                    (unsigned int)((const unsigned short*)wnorm)[g] << 16);
            const float a = nrm * (2.0f / 7.0f);
            const float b = -nrm;
            const unsigned int bits0 =
                (unsigned)w0.x | ((unsigned)w0.y << 8) | ((unsigned)w1.x << 16);
            const unsigned int bits1 =
                (unsigned)w1.y | ((unsigned)w2.x << 8) | ((unsigned)w2.y << 16);
            unsigned int packs[8];
#pragma unroll
            for (int t3 = 0; t3 < 2; ++t3) {
                const unsigned int bits = t3 ? bits1 : bits0;
#pragma unroll
                for (int j = 0; j < 4; ++j) {
                    const float f0 = fmaf((float)((bits >> (6 * j)) & 7), a, b);
                    const float f1 = fmaf((float)((bits >> (6 * j + 3)) & 7), a, b);
                    packs[t3 * 4 + j] = pack2_bf16(f0, f1);
                }
            }
            unsigned int* dst = (unsigned int*)&Bs[bn_local * LDK + bkg * 32 + half * 16];
            *(uint4*)dst       = make_uint4(packs[0], packs[1], packs[2], packs[3]);
            *(uint4*)(dst + 4) = make_uint4(packs[4], packs[5], packs[6], packs[7]);
        }
        __syncthreads();
#pragma unroll
        for (int ks = 0; ks < 2; ++ks) {
            const int kb = ks * 32 + quad * 8;
            bf16x8 aF[4], bF[2];
#pragma unroll
            for (int mi = 0; mi < 4; ++mi)
                aF[mi] = *(const bf16x8*)&As[(wm + mi * 16 + lm) * LDK + kb];
#pragma unroll
            for (int ni = 0; ni < 2; ++ni)
                bF[ni] = *(const bf16x8*)&Bs[(wn + ni * 16 + lm) * LDK + kb];
#pragma unroll
            for (int mi = 0; mi < 4; ++mi)
#pragma unroll
                for (int ni = 0; ni < 2; ++ni)
                    acc[mi][ni] = __builtin_amdgcn_mfma_f32_16x16x32_bf16(
                        aF[mi], bF[ni], acc[mi][ni], 0, 0, 0);
        }
    }
#pragma unroll
    for (int ni = 0; ni < 2; ++ni) {
        const int o  = n0 + wn + ni * 16 + lm;
        const float bv = bias[o];
#pragma unroll
        for (int mi = 0; mi < 4; ++mi)
#pragma unroll
            for (int r = 0; r < 4; ++r) {
                const int m = m0 + wm + mi * 16 + quad * 4 + r;
                out[m * N_TOTAL + o] = acc[mi][ni][r] + bv;
            }
    }
}

extern "C" void kernel_launch(void* const* d_in, const int* in_sizes, int n_in,
                              void* d_out, int out_size, void* d_ws, size_t ws_size,
                              hipStream_t stream) {
    const float* x    = (const float*)d_in[0];
    const int*   wq   = (const int*)d_in[1];
    const void*  wn   = d_in[2];
    const float* bias = (const float*)d_in[3];
    float* out = (float*)d_out;

    const size_t xh_off = 256;
    const size_t xh_sz  = (size_t)M_TOTAL * K_TOTAL * 2;          // 4 MB
    const size_t np_off = xh_off + xh_sz;
    const size_t np_sz  = (size_t)NUM_GROUPS * 4;                 // 5.6 MB
    const size_t need   = np_off + np_sz;

    if (ws_size >= need) {
        unsigned short* xh = (unsigned short*)((char*)d_ws + xh_off);
        unsigned int*   np = (unsigned int*)((char*)d_ws + np_off);
        convert_x_t_kernel<<<(M_TOTAL / 32) * (K_TOTAL / 64), 256, 0, stream>>>(x, xh);
        norm_pack_kernel<<<(NUM_GROUPS + 511) / 512, 512, 0, stream>>>(wn, np);
        l3b_gemm_pipe<<<(M_TOTAL / BM) * (N_TOTAL / BN), 512, 0, stream>>>(
            (const _Float16*)xh, wq, np, bias, out);
    } else {
        dim3 grid(N_TOTAL / 64, M_TOTAL / 128);
        l3b_gemm_kernel<<<grid, 256, 0, stream>>>(x, wq, wn, bias, out);
    }
}